// Round 3
// baseline (963.618 us; speedup 1.0000x reference)
//
#include <hip/hip_runtime.h>
#include <hip/hip_bf16.h>
#include <math.h>

#define B_    8
#define SEQ_  4096
#define CIN_  7
#define DM_   512
#define NL_   4
#define PL_   16
#define NP_   256
#define NS_   16
#define DC_   4
#define DI_   1024
#define DTR_  32
#define CD_   64
#define PRED_ 96
#define TOK_  (B_*NP_)   // 2048
#define EPS_  1e-5f
#define CL_   32         // scan chunk length
#define NCH_  (NP_/CL_)  // 8 chunks

typedef unsigned short u16;
typedef __attribute__((ext_vector_type(8))) short short8;
typedef __attribute__((ext_vector_type(4))) float floatx4;

__device__ __forceinline__ float silu_f(float x){ return x / (1.f + __expf(-x)); }
__device__ __forceinline__ float softplus_f(float x){ return x > 20.f ? x : log1pf(__expf(x)); }
__device__ __forceinline__ u16 f2bf(float f){
  union { __hip_bfloat16 h; u16 u; } cv; cv.h = __float2bfloat16(f); return cv.u;
}
#define GLDS16(g, l) __builtin_amdgcn_global_load_lds( \
    (const __attribute__((address_space(1))) void*)(g), \
    (__attribute__((address_space(3))) void*)(l), 16, 0, 0)

// ---------------- LN over CIN=7 (input) ----------------
__global__ void ln7_kernel(const float* __restrict__ x, const float* __restrict__ g,
                           const float* __restrict__ b, float* __restrict__ o){
  int i = blockIdx.x*256 + threadIdx.x; // over B*SEQ
  if (i >= B_*SEQ_) return;
  float v[CIN_]; float m = 0.f;
  #pragma unroll
  for (int c=0;c<CIN_;c++){ v[c]=x[i*CIN_+c]; m+=v[c]; }
  m *= (1.f/CIN_);
  float var = 0.f;
  #pragma unroll
  for (int c=0;c<CIN_;c++){ float d=v[c]-m; var+=d*d; }
  var *= (1.f/CIN_);
  float r = rsqrtf(var + EPS_);
  #pragma unroll
  for (int c=0;c<CIN_;c++) o[i*CIN_+c] = (v[c]-m)*r*g[c]+b[c];
}

// ---------------- patch embed ----------------
__global__ __launch_bounds__(256) void embed_kernel(const float* __restrict__ xln,
    const float* __restrict__ peW, const float* __restrict__ peb, float* __restrict__ h){
  __shared__ float sp[112];
  int bn = blockIdx.x;            // b*256 + n
  int b = bn >> 8, n = bn & 255;
  int tid = threadIdx.x;
  if (tid < 112){
    int c = tid >> 4, p = tid & 15;
    sp[tid] = xln[((size_t)b*SEQ_ + n*PL_ + p)*CIN_ + c];
  }
  __syncthreads();
  #pragma unroll
  for (int half = 0; half < 2; half++){
    int d = tid + half*256;
    float acc = peb[d];
    const float* w = peW + d*112;
    #pragma unroll 14
    for (int k = 0; k < 112; k++) acc += sp[k]*w[k];
    h[(size_t)bn*DM_ + d] = acc;
  }
}

// ---------------- LN over DM=512 (fp32 out + bf16 out) ----------------
__global__ __launch_bounds__(256) void ln512_kernel(const float* __restrict__ in,
    const float* __restrict__ g, const float* __restrict__ b,
    float* __restrict__ out, u16* __restrict__ outb){
  __shared__ float red[256];
  int t = blockIdx.x, tid = threadIdx.x;
  float v0 = in[(size_t)t*DM_+tid], v1 = in[(size_t)t*DM_+tid+256];
  red[tid] = v0+v1; __syncthreads();
  for (int s=128;s>0;s>>=1){ if (tid<s) red[tid]+=red[tid+s]; __syncthreads(); }
  float m = red[0] * (1.f/DM_); __syncthreads();
  float d0 = v0-m, d1 = v1-m;
  red[tid] = d0*d0+d1*d1; __syncthreads();
  for (int s=128;s>0;s>>=1){ if (tid<s) red[tid]+=red[tid+s]; __syncthreads(); }
  float r = rsqrtf(red[0]*(1.f/DM_) + EPS_);
  float o0 = d0*r*g[tid]+b[tid];
  float o1 = d1*r*g[tid+256]+b[tid+256];
  out[(size_t)t*DM_+tid]     = o0;
  out[(size_t)t*DM_+tid+256] = o1;
  outb[(size_t)t*DM_+tid]     = f2bf(o0);
  outb[(size_t)t*DM_+tid+256] = f2bf(o1);
}

// ---------------- bf16 MFMA NT GEMM: C[M,N](f32) = A[M,K]*B[N,K]^T ----------------
// BK=64. global_load_lds(16B) staging with XOR seg swizzle: LDS slot (row, s)
// holds global k-seg s^(row&7); frag ds_read_b128 hits 2 lanes/bank-granule (free).
template<int BM, int BN, bool ACC>
__global__ __launch_bounds__(256) void gemm_bf16(const u16* __restrict__ A,
    const u16* __restrict__ Bw, float* __restrict__ C, int K, int lda, int ldb, int ldc){
  constexpr int MI = BM/32, NI = BN/32;
  __shared__ __align__(16) u16 As[BM*64];
  __shared__ __align__(16) u16 Bs[BN*64];
  int tid = threadIdx.x;
  int wave = __builtin_amdgcn_readfirstlane(tid>>6);
  int lane = tid&63;
  int wm = wave>>1, wn = wave&1;
  int quad = lane>>4, l16 = lane&15;
  int bm = blockIdx.y*BM, bn = blockIdx.x*BN;
  int r8 = lane>>3, sseg = lane&7;
  int gseg = sseg ^ r8;                  // global k-seg this lane fetches
  floatx4 acc[MI][NI] = {};
  for (int k0 = 0; k0 < K; k0 += 64){
    #pragma unroll
    for (int r = 0; r < BM/32; r++){
      int rowb = (r*4 + wave)*8;
      const u16* gp = A + (size_t)(bm + rowb + r8)*lda + k0 + gseg*8;
      GLDS16(gp, &As[rowb*64]);
    }
    #pragma unroll
    for (int r = 0; r < BN/32; r++){
      int rowb = (r*4 + wave)*8;
      const u16* gp = Bw + (size_t)(bn + rowb + r8)*ldb + k0 + gseg*8;
      GLDS16(gp, &Bs[rowb*64]);
    }
    __syncthreads();
    #pragma unroll
    for (int kh = 0; kh < 2; kh++){
      short8 af[MI], bfr[NI];
      #pragma unroll
      for (int i = 0; i < MI; i++){
        int row = wm*(BM/2)+i*16+l16;
        af[i] = *(short8*)&As[row*64 + (((kh*4+quad)^(row&7))*8)];
      }
      #pragma unroll
      for (int j = 0; j < NI; j++){
        int row = wn*(BN/2)+j*16+l16;
        bfr[j] = *(short8*)&Bs[row*64 + (((kh*4+quad)^(row&7))*8)];
      }
      #pragma unroll
      for (int i = 0; i < MI; i++)
        #pragma unroll
        for (int j = 0; j < NI; j++)
          acc[i][j] = __builtin_amdgcn_mfma_f32_16x16x32_bf16(af[i], bfr[j], acc[i][j], 0, 0, 0);
    }
    __syncthreads();
  }
  #pragma unroll
  for (int i = 0; i < MI; i++){
    #pragma unroll
    for (int j = 0; j < NI; j++){
      #pragma unroll
      for (int r = 0; r < 4; r++){
        int m  = bm + wm*(BM/2) + i*16 + quad*4 + r;
        int nn = bn + wn*(BN/2) + j*16 + l16;
        if (ACC) C[(size_t)m*ldc+nn] += acc[i][j][r];
        else     C[(size_t)m*ldc+nn]  = acc[i][j][r];
      }
    }
  }
}

// ---------------- causal depthwise conv (DC=4) + bias + silu ----------------
__global__ void conv_silu_kernel(const float* __restrict__ xz, const float* __restrict__ cW,
                                 const float* __restrict__ cb, float* __restrict__ xc){
  int idx = blockIdx.x*256 + threadIdx.x;   // TOK*DI
  if (idx >= TOK_*DI_) return;
  int c = idx & (DI_-1); int t = idx >> 10; int l = t & (NP_-1);
  float acc = cb[c];
  const float* w = cW + c*DC_;
  #pragma unroll
  for (int k = 0; k < DC_; k++){
    int ls = l - (DC_-1) + k;
    if (ls >= 0) acc += xz[(size_t)(t - l + ls)*(2*DI_) + c] * w[k];
  }
  xc[idx] = silu_f(acc);
}

// ---------------- dbl[t,e] = sum_k xc[t,k]*W_x[e,k] ----------------
__global__ __launch_bounds__(256) void dbl_kernel(const float* __restrict__ xc,
    const float* __restrict__ wxT, float* __restrict__ dbl){
  int wave = threadIdx.x >> 6; int lane = threadIdx.x & 63;
  int t = blockIdx.x*4 + wave;
  const float* xr = xc + (size_t)t*DI_;
  float acc = 0.f;
  for (int k = 0; k < DI_; k += 4){
    float4 xv = *(const float4*)(xr + k);
    acc += xv.x*wxT[(k+0)*64+lane];
    acc += xv.y*wxT[(k+1)*64+lane];
    acc += xv.z*wxT[(k+2)*64+lane];
    acc += xv.w*wxT[(k+3)*64+lane];
  }
  dbl[(size_t)t*64 + lane] = acc;
}

// ---------------- delta = softplus(dt @ W_dt^T + b_dt) ----------------
__global__ __launch_bounds__(256) void delta_kernel(const float* __restrict__ dbl,
    const float* __restrict__ wdtT, const float* __restrict__ bdt, float* __restrict__ delta){
  __shared__ float sdt[DTR_];
  int t = blockIdx.y; int d = blockIdx.x*256 + threadIdx.x;
  if (threadIdx.x < DTR_) sdt[threadIdx.x] = dbl[(size_t)t*64 + threadIdx.x];
  __syncthreads();
  float acc = bdt[d];
  #pragma unroll
  for (int r = 0; r < DTR_; r++) acc += sdt[r]*wdtT[r*DI_ + d];
  delta[(size_t)t*DI_ + d] = softplus_f(acc);
}

// ---------------- chunked selective scan ----------------
// Pass A: per (b,chunk,d,n): aprod = prod(a_t), hend = local scan from 0.
__global__ __launch_bounds__(256) void scan_part_kernel(const float* __restrict__ delta,
    const float* __restrict__ xc, const float* __restrict__ dbl,
    const float* __restrict__ Alog, float* __restrict__ hend, float* __restrict__ aprod){
  int tid = threadIdx.x;
  int n = tid & 15, dg = tid >> 4;
  int d = blockIdx.x*16 + dg;
  int bych = blockIdx.y;                 // b*NCH + ch
  int b = bych >> 3, ch = bych & 7;
  float A = -__expf(Alog[d*NS_ + n]);
  int base = b*NP_ + ch*CL_;
  float h = 0.f, prod = 1.f;
  #pragma unroll 8
  for (int t = 0; t < CL_; t++){
    int row = base + t;
    float de = delta[(size_t)row*DI_ + d];
    float xv = xc[(size_t)row*DI_ + d];
    float Bv = dbl[(size_t)row*64 + 32 + n];
    float a = __expf(de*A);
    h = a*h + de*Bv*xv;
    prod *= a;
  }
  int idx = ((size_t)bych*DI_ + d)*NS_ + n;
  hend[idx] = h; aprod[idx] = prod;
}

// Pass B: prefix over chunks -> h_in per chunk.
__global__ __launch_bounds__(256) void scan_fix_kernel(const float* __restrict__ aprod,
    const float* __restrict__ hend, float* __restrict__ hin){
  int id = blockIdx.x*256 + threadIdx.x;  // over B*DI*NS = 131072
  int nd = id & (DI_*NS_ - 1);            // (d,n) packed
  int b  = id >> 14;
  float h = 0.f;
  #pragma unroll
  for (int ch = 0; ch < NCH_; ch++){
    size_t idx = (size_t)(b*NCH_ + ch)*(DI_*NS_) + nd;
    hin[idx] = h;
    h = aprod[idx]*h + hend[idx];
  }
}

// Pass C: replay chunk from h_in, reduce y over n, fuse ymix -> bf16 out.
__global__ __launch_bounds__(256) void scan_final_kernel(const float* __restrict__ delta,
    const float* __restrict__ xc, const float* __restrict__ dbl,
    const float* __restrict__ xz, const float* __restrict__ Dv,
    const float* __restrict__ Alog, const float* __restrict__ hin,
    u16* __restrict__ yb){
  int tid = threadIdx.x;
  int n = tid & 15, dg = tid >> 4;
  int d = blockIdx.x*16 + dg;
  int bych = blockIdx.y;
  int b = bych >> 3, ch = bych & 7;
  float A = -__expf(Alog[d*NS_ + n]);
  float Dvd = Dv[d];
  int base = b*NP_ + ch*CL_;
  float h = hin[((size_t)bych*DI_ + d)*NS_ + n];
  #pragma unroll 8
  for (int t = 0; t < CL_; t++){
    int row = base + t;
    float de = delta[(size_t)row*DI_ + d];
    float xv = xc[(size_t)row*DI_ + d];
    float Bv = dbl[(size_t)row*64 + 32 + n];
    float Cv = dbl[(size_t)row*64 + 48 + n];
    float z  = xz[(size_t)row*(2*DI_) + DI_ + d];
    float a = __expf(de*A);
    h = a*h + de*Bv*xv;
    float p = h*Cv;
    p += __shfl_xor(p,1); p += __shfl_xor(p,2); p += __shfl_xor(p,4); p += __shfl_xor(p,8);
    if (n == 0) yb[(size_t)row*DI_ + d] = f2bf((p + xv*Dvd) * silu_f(z));
  }
}

// ---------------- head GEMM1 partials ----------------
__global__ __launch_bounds__(256) void head1_kernel(const float* __restrict__ u,
    const float* __restrict__ hW1, float* __restrict__ partial){
  const int KTOT = DM_*NP_;        // 131072
  const int KLEN = KTOT/16;        // 8192
  int nidx = blockIdx.x;           // 0..127
  int kc   = blockIdx.y;           // 0..15
  int tid  = threadIdx.x;
  float acc[8] = {};
  const float* w = hW1 + (size_t)nidx*KTOT;
  for (int k = kc*KLEN + tid; k < (kc+1)*KLEN; k += 256){
    float wv = w[k];
    #pragma unroll
    for (int m = 0; m < 8; m++) acc[m] += u[(size_t)m*KTOT + k]*wv;
  }
  __shared__ float red[256];
  #pragma unroll
  for (int m = 0; m < 8; m++){
    red[tid] = acc[m]; __syncthreads();
    for (int s=128;s>0;s>>=1){ if (tid<s) red[tid]+=red[tid+s]; __syncthreads(); }
    if (tid == 0) partial[((size_t)kc*128 + nidx)*8 + m] = red[0];
    __syncthreads();
  }
}

__global__ void head_combine_kernel(const float* __restrict__ partial,
    const float* __restrict__ hb1, float* __restrict__ t1){
  int idx = blockIdx.x*256 + threadIdx.x;  // n*8+m, 1024 total
  if (idx >= 128*8) return;
  int n = idx >> 3, m = idx & 7;
  float s = hb1[n];
  #pragma unroll
  for (int kc = 0; kc < 16; kc++) s += partial[((size_t)kc*128 + n)*8 + m];
  float ge = 0.5f*s*(1.f + erff(s*0.70710678118f));
  t1[m*128 + n] = ge;
}

__global__ void head2_kernel(const float* __restrict__ t1, const float* __restrict__ hW2,
                             const float* __restrict__ hb2, float* __restrict__ out){
  int idx = blockIdx.x*128 + threadIdx.x;  // 8*96
  if (idx >= B_*PRED_) return;
  int m = idx / PRED_, q = idx % PRED_;
  float s = hb2[q];
  #pragma unroll 16
  for (int k = 0; k < 2*CD_; k++) s += t1[m*128 + k]*hW2[q*128 + k];
  out[idx] = s;
}

// ---------------- prep: transposes + bf16 weight conversions ----------------
__global__ void prep_kernel(const float* __restrict__ W_dt, const float* __restrict__ W_x,
                            const float* __restrict__ W_in, const float* __restrict__ W_out,
                            float* __restrict__ wdtT, float* __restrict__ wxT,
                            u16* __restrict__ WinB, u16* __restrict__ WoutB){
  int idx = blockIdx.x*256 + threadIdx.x;
  if (idx < NL_*DTR_*DI_){
    int l = idx / (DTR_*DI_); int rem = idx % (DTR_*DI_);
    int r = rem / DI_; int d = rem % DI_;
    wdtT[idx] = W_dt[((size_t)l*DI_ + d)*DTR_ + r];
  }
  if (idx < NL_*DI_*64){
    int l = idx / (DI_*64); int rem = idx % (DI_*64);
    int k = rem / 64; int e = rem % 64;
    wxT[idx] = W_x[((size_t)l*64 + e)*DI_ + k];
  }
  if (idx < NL_*2*DI_*DM_) WinB[idx]  = f2bf(W_in[idx]);
  if (idx < NL_*DM_*DI_)   WoutB[idx] = f2bf(W_out[idx]);
}

extern "C" void kernel_launch(void* const* d_in, const int* in_sizes, int n_in,
                              void* d_out, int out_size, void* d_ws, size_t ws_size,
                              hipStream_t stream) {
  const float* x      = (const float*)d_in[0];
  const float* in_g   = (const float*)d_in[1];
  const float* in_b   = (const float*)d_in[2];
  const float* pe_W   = (const float*)d_in[3];
  const float* pe_b   = (const float*)d_in[4];
  const float* ln_g   = (const float*)d_in[5];
  const float* ln_b   = (const float*)d_in[6];
  const float* W_in   = (const float*)d_in[7];
  const float* conv_W = (const float*)d_in[8];
  const float* conv_b = (const float*)d_in[9];
  const float* W_x    = (const float*)d_in[10];
  const float* W_dt   = (const float*)d_in[11];
  const float* b_dt   = (const float*)d_in[12];
  const float* A_log  = (const float*)d_in[13];
  const float* Dskip  = (const float*)d_in[14];
  const float* W_out  = (const float*)d_in[15];
  const float* fn_g   = (const float*)d_in[16];
  const float* fn_b   = (const float*)d_in[17];
  const float* hW1    = (const float*)d_in[18];
  const float* hb1    = (const float*)d_in[19];
  const float* hW2    = (const float*)d_in[20];
  const float* hb2    = (const float*)d_in[21];

  float* ws    = (float*)d_ws;
  float* h     = ws;                    // 1,048,576 f
  float* un    = h     + 1048576;       // 1,048,576 f   (fp32 un; reused as hin during layers)
  float* xz    = un    + 1048576;       // 4,194,304 f
  float* xc    = xz    + 4194304;       // 2,097,152 f
  float* dblb  = xc    + 2097152;       //   131,072 f
  float* delta = dblb  + 131072;        // 2,097,152 f
  float* y     = delta + 2097152;       // 2,097,152 f   (reused: hend + aprod)
  float* wdtT  = y     + 2097152;       //   131,072 f
  float* wxT   = wdtT  + 131072;        //   262,144 f
  float* bf_rgn= wxT   + 262144;
  u16*   unb   = (u16*)bf_rgn;                  // 1,048,576 u16
  u16*   yb    = (u16*)(bf_rgn + 524288);       // 2,097,152 u16
  u16*   WinB  = (u16*)(bf_rgn + 524288 + 1048576);            // 4,194,304 u16
  u16*   WoutB = (u16*)(bf_rgn + 524288 + 1048576 + 2097152);  // 2,097,152 u16
  // total: 17,825,792 floats = 71.3 MB
  float* hend  = y;                     // 1,048,576 f
  float* aprod = y + 1048576;           // 1,048,576 f
  float* hin   = un;                    // 1,048,576 f (un fp32 only needed for final head)
  float* xln     = y;                   // prologue-only, overlays y
  float* partial = xz;                  // epilogue-only, overlays xz
  float* t1      = xz + 16384;

  prep_kernel<<<16384, 256, 0, stream>>>(W_dt, W_x, W_in, W_out, wdtT, wxT, WinB, WoutB);
  ln7_kernel<<<(B_*SEQ_+255)/256, 256, 0, stream>>>(x, in_g, in_b, xln);
  embed_kernel<<<TOK_, 256, 0, stream>>>(xln, pe_W, pe_b, h);

  for (int l = 0; l < NL_; l++){
    ln512_kernel<<<TOK_, 256, 0, stream>>>(h, ln_g + l*DM_, ln_b + l*DM_, un, unb);
    gemm_bf16<128,128,false><<<dim3(2*DI_/128, TOK_/128), 256, 0, stream>>>(
        unb, WinB + (size_t)l*2*DI_*DM_, xz, DM_, DM_, DM_, 2*DI_);
    conv_silu_kernel<<<(TOK_*DI_)/256, 256, 0, stream>>>(
        xz, conv_W + (size_t)l*DI_*DC_, conv_b + (size_t)l*DI_, xc);
    dbl_kernel<<<TOK_/4, 256, 0, stream>>>(xc, wxT + (size_t)l*DI_*64, dblb);
    delta_kernel<<<dim3(DI_/256, TOK_), 256, 0, stream>>>(
        dblb, wdtT + (size_t)l*DTR_*DI_, b_dt + (size_t)l*DI_, delta);
    scan_part_kernel<<<dim3(DI_/16, B_*NCH_), 256, 0, stream>>>(
        delta, xc, dblb, A_log + (size_t)l*DI_*NS_, hend, aprod);
    scan_fix_kernel<<<(B_*DI_*NS_)/256, 256, 0, stream>>>(aprod, hend, hin);
    scan_final_kernel<<<dim3(DI_/16, B_*NCH_), 256, 0, stream>>>(
        delta, xc, dblb, xz, Dskip + (size_t)l*DI_, A_log + (size_t)l*DI_*NS_, hin, yb);
    gemm_bf16<64,64,true><<<dim3(DM_/64, TOK_/64), 256, 0, stream>>>(
        yb, WoutB + (size_t)l*DM_*DI_, h, DI_, DI_, DI_, DM_);
  }

  ln512_kernel<<<TOK_, 256, 0, stream>>>(h, fn_g, fn_b, un, unb);
  head1_kernel<<<dim3(128, 16), 256, 0, stream>>>(un, hW1, partial);
  head_combine_kernel<<<4, 256, 0, stream>>>(partial, hb1, t1);
  head2_kernel<<<6, 128, 0, stream>>>(t1, hW2, hb2, (float*)d_out);
}

// Round 4
// 796.964 us; speedup vs baseline: 1.2091x; 1.2091x over previous
//
#include <hip/hip_runtime.h>
#include <hip/hip_bf16.h>
#include <math.h>

#define B_    8
#define SEQ_  4096
#define CIN_  7
#define DM_   512
#define NL_   4
#define PL_   16
#define NP_   256
#define NS_   16
#define DC_   4
#define DI_   1024
#define DTR_  32
#define CD_   64
#define PRED_ 96
#define TOK_  (B_*NP_)   // 2048
#define EPS_  1e-5f
#define CL_   16         // scan chunk length
#define NCH_  (NP_/CL_)  // 16 chunks

typedef unsigned short u16;
typedef __attribute__((ext_vector_type(8))) short short8;
typedef __attribute__((ext_vector_type(4))) float floatx4;

__device__ __forceinline__ float silu_f(float x){ return x / (1.f + __expf(-x)); }
__device__ __forceinline__ float softplus_f(float x){ return x > 20.f ? x : log1pf(__expf(x)); }
__device__ __forceinline__ u16 f2bf(float f){
  union { __hip_bfloat16 h; u16 u; } cv; cv.h = __float2bfloat16(f); return cv.u;
}
#define GLDS16(g, l) __builtin_amdgcn_global_load_lds( \
    (const __attribute__((address_space(1))) void*)(g), \
    (__attribute__((address_space(3))) void*)(l), 16, 0, 0)

// ---------------- LN over CIN=7 (input) ----------------
__global__ void ln7_kernel(const float* __restrict__ x, const float* __restrict__ g,
                           const float* __restrict__ b, float* __restrict__ o){
  int i = blockIdx.x*256 + threadIdx.x; // over B*SEQ
  if (i >= B_*SEQ_) return;
  float v[CIN_]; float m = 0.f;
  #pragma unroll
  for (int c=0;c<CIN_;c++){ v[c]=x[i*CIN_+c]; m+=v[c]; }
  m *= (1.f/CIN_);
  float var = 0.f;
  #pragma unroll
  for (int c=0;c<CIN_;c++){ float d=v[c]-m; var+=d*d; }
  var *= (1.f/CIN_);
  float r = rsqrtf(var + EPS_);
  #pragma unroll
  for (int c=0;c<CIN_;c++) o[i*CIN_+c] = (v[c]-m)*r*g[c]+b[c];
}

// ---------------- patch embed ----------------
__global__ __launch_bounds__(256) void embed_kernel(const float* __restrict__ xln,
    const float* __restrict__ peW, const float* __restrict__ peb, float* __restrict__ h){
  __shared__ float sp[112];
  int bn = blockIdx.x;            // b*256 + n
  int b = bn >> 8, n = bn & 255;
  int tid = threadIdx.x;
  if (tid < 112){
    int c = tid >> 4, p = tid & 15;
    sp[tid] = xln[((size_t)b*SEQ_ + n*PL_ + p)*CIN_ + c];
  }
  __syncthreads();
  #pragma unroll
  for (int half = 0; half < 2; half++){
    int d = tid + half*256;
    float acc = peb[d];
    const float* w = peW + d*112;
    #pragma unroll 14
    for (int k = 0; k < 112; k++) acc += sp[k]*w[k];
    h[(size_t)bn*DM_ + d] = acc;
  }
}

// ---------------- LN over DM=512 (fp32 out + bf16 out) ----------------
__global__ __launch_bounds__(256) void ln512_kernel(const float* __restrict__ in,
    const float* __restrict__ g, const float* __restrict__ b,
    float* __restrict__ out, u16* __restrict__ outb){
  __shared__ float red[256];
  int t = blockIdx.x, tid = threadIdx.x;
  float v0 = in[(size_t)t*DM_+tid], v1 = in[(size_t)t*DM_+tid+256];
  red[tid] = v0+v1; __syncthreads();
  for (int s=128;s>0;s>>=1){ if (tid<s) red[tid]+=red[tid+s]; __syncthreads(); }
  float m = red[0] * (1.f/DM_); __syncthreads();
  float d0 = v0-m, d1 = v1-m;
  red[tid] = d0*d0+d1*d1; __syncthreads();
  for (int s=128;s>0;s>>=1){ if (tid<s) red[tid]+=red[tid+s]; __syncthreads(); }
  float r = rsqrtf(red[0]*(1.f/DM_) + EPS_);
  float o0 = d0*r*g[tid]+b[tid];
  float o1 = d1*r*g[tid+256]+b[tid+256];
  out[(size_t)t*DM_+tid]     = o0;
  out[(size_t)t*DM_+tid+256] = o1;
  outb[(size_t)t*DM_+tid]     = f2bf(o0);
  outb[(size_t)t*DM_+tid+256] = f2bf(o1);
}

// ---------------- bf16 MFMA NT GEMM: C[M,N](f32) = A[M,K]*B[N,K]^T ----------------
// BK=64. global_load_lds(16B) staging with XOR seg swizzle.
template<int BM, int BN, bool ACC>
__global__ __launch_bounds__(256) void gemm_bf16(const u16* __restrict__ A,
    const u16* __restrict__ Bw, float* __restrict__ C, int K, int lda, int ldb, int ldc){
  constexpr int MI = BM/32, NI = BN/32;
  __shared__ __align__(16) u16 As[BM*64];
  __shared__ __align__(16) u16 Bs[BN*64];
  int tid = threadIdx.x;
  int wave = __builtin_amdgcn_readfirstlane(tid>>6);
  int lane = tid&63;
  int wm = wave>>1, wn = wave&1;
  int quad = lane>>4, l16 = lane&15;
  int bm = blockIdx.y*BM, bn = blockIdx.x*BN;
  int r8 = lane>>3, sseg = lane&7;
  int gseg = sseg ^ r8;                  // global k-seg this lane fetches
  floatx4 acc[MI][NI] = {};
  for (int k0 = 0; k0 < K; k0 += 64){
    #pragma unroll
    for (int r = 0; r < BM/32; r++){
      int rowb = (r*4 + wave)*8;
      const u16* gp = A + (size_t)(bm + rowb + r8)*lda + k0 + gseg*8;
      GLDS16(gp, &As[rowb*64]);
    }
    #pragma unroll
    for (int r = 0; r < BN/32; r++){
      int rowb = (r*4 + wave)*8;
      const u16* gp = Bw + (size_t)(bn + rowb + r8)*ldb + k0 + gseg*8;
      GLDS16(gp, &Bs[rowb*64]);
    }
    __syncthreads();
    #pragma unroll
    for (int kh = 0; kh < 2; kh++){
      short8 af[MI], bfr[NI];
      #pragma unroll
      for (int i = 0; i < MI; i++){
        int row = wm*(BM/2)+i*16+l16;
        af[i] = *(short8*)&As[row*64 + (((kh*4+quad)^(row&7))*8)];
      }
      #pragma unroll
      for (int j = 0; j < NI; j++){
        int row = wn*(BN/2)+j*16+l16;
        bfr[j] = *(short8*)&Bs[row*64 + (((kh*4+quad)^(row&7))*8)];
      }
      #pragma unroll
      for (int i = 0; i < MI; i++)
        #pragma unroll
        for (int j = 0; j < NI; j++)
          acc[i][j] = __builtin_amdgcn_mfma_f32_16x16x32_bf16(af[i], bfr[j], acc[i][j], 0, 0, 0);
    }
    __syncthreads();
  }
  #pragma unroll
  for (int i = 0; i < MI; i++){
    #pragma unroll
    for (int j = 0; j < NI; j++){
      #pragma unroll
      for (int r = 0; r < 4; r++){
        int m  = bm + wm*(BM/2) + i*16 + quad*4 + r;
        int nn = bn + wn*(BN/2) + j*16 + l16;
        if (ACC) C[(size_t)m*ldc+nn] += acc[i][j][r];
        else     C[(size_t)m*ldc+nn]  = acc[i][j][r];
      }
    }
  }
}

// ---------------- causal depthwise conv (DC=4) + bias + silu ----------------
__global__ void conv_silu_kernel(const float* __restrict__ xz, const float* __restrict__ cW,
                                 const float* __restrict__ cb, float* __restrict__ xc){
  int idx = blockIdx.x*256 + threadIdx.x;   // TOK*DI
  if (idx >= TOK_*DI_) return;
  int c = idx & (DI_-1); int t = idx >> 10; int l = t & (NP_-1);
  float acc = cb[c];
  const float* w = cW + c*DC_;
  #pragma unroll
  for (int k = 0; k < DC_; k++){
    int ls = l - (DC_-1) + k;
    if (ls >= 0) acc += xz[(size_t)(t - l + ls)*(2*DI_) + c] * w[k];
  }
  xc[idx] = silu_f(acc);
}

// ---------------- dbl[t,e] = sum_k xc[t,k]*W_x[e,k] ----------------
__global__ __launch_bounds__(256) void dbl_kernel(const float* __restrict__ xc,
    const float* __restrict__ wxT, float* __restrict__ dbl){
  int wave = threadIdx.x >> 6; int lane = threadIdx.x & 63;
  int t = blockIdx.x*4 + wave;
  const float* xr = xc + (size_t)t*DI_;
  float acc = 0.f;
  for (int k = 0; k < DI_; k += 4){
    float4 xv = *(const float4*)(xr + k);
    acc += xv.x*wxT[(k+0)*64+lane];
    acc += xv.y*wxT[(k+1)*64+lane];
    acc += xv.z*wxT[(k+2)*64+lane];
    acc += xv.w*wxT[(k+3)*64+lane];
  }
  dbl[(size_t)t*64 + lane] = acc;
}

// ---------------- delta = softplus(dt @ W_dt^T + b_dt) ----------------
__global__ __launch_bounds__(256) void delta_kernel(const float* __restrict__ dbl,
    const float* __restrict__ wdtT, const float* __restrict__ bdt, float* __restrict__ delta){
  __shared__ float sdt[DTR_];
  int t = blockIdx.y; int d = blockIdx.x*256 + threadIdx.x;
  if (threadIdx.x < DTR_) sdt[threadIdx.x] = dbl[(size_t)t*64 + threadIdx.x];
  __syncthreads();
  float acc = bdt[d];
  #pragma unroll
  for (int r = 0; r < DTR_; r++) acc += sdt[r]*wdtT[r*DI_ + d];
  delta[(size_t)t*DI_ + d] = softplus_f(acc);
}

// ---------------- chunked selective scan, d-per-lane (16 n-states in registers) ----------------
// Pass A: per (b,ch,d): aprod[n] = prod(a_t), hend[n] = local scan from 0.
__global__ __launch_bounds__(256) void scan_part_kernel(const float* __restrict__ delta,
    const float* __restrict__ xc, const float* __restrict__ dbl,
    const float* __restrict__ Alog, float* __restrict__ hend, float* __restrict__ aprod){
  __shared__ float sBC[CL_][32];
  int tid = threadIdx.x;
  int d = blockIdx.x*256 + tid;
  int bych = blockIdx.y;               // b*NCH + ch
  int b = bych >> 4, ch = bych & (NCH_-1);
  int base = b*NP_ + ch*CL_;
  for (int i = tid; i < CL_*32; i += 256){
    int t = i >> 5, c = i & 31;
    sBC[t][c] = dbl[(size_t)(base+t)*64 + 32 + c];
  }
  float A[NS_], h[NS_], pr[NS_];
  #pragma unroll
  for (int k = 0; k < NS_; k++){
    A[k] = -__expf(Alog[(size_t)d*NS_ + k]);
    h[k] = 0.f; pr[k] = 1.f;
  }
  __syncthreads();
  #pragma unroll
  for (int t = 0; t < CL_; t++){
    int row = base + t;
    float de = delta[(size_t)row*DI_ + d];
    float xv = xc[(size_t)row*DI_ + d];
    float cde = de*xv;
    #pragma unroll
    for (int k = 0; k < NS_; k++){
      float a = __expf(de*A[k]);
      h[k] = a*h[k] + cde*sBC[t][k];
      pr[k] *= a;
    }
  }
  size_t o = ((size_t)bych*DI_ + d)*NS_;
  #pragma unroll
  for (int k = 0; k < NS_; k++){ hend[o+k] = h[k]; aprod[o+k] = pr[k]; }
}

// Pass B: in-place prefix over chunks: hend[ch] <- h_in(ch).
__global__ __launch_bounds__(256) void scan_fix_kernel(const float* __restrict__ aprod,
    float* __restrict__ hend){
  int id = blockIdx.x*256 + threadIdx.x;  // over B*DI*NS = 131072
  int nd = id & (DI_*NS_ - 1);            // (d,n) packed
  int b  = id >> 14;
  float h = 0.f;
  #pragma unroll
  for (int ch = 0; ch < NCH_; ch++){
    size_t idx = (size_t)(b*NCH_ + ch)*(DI_*NS_) + nd;
    float ap = aprod[idx];
    float he = hend[idx];
    hend[idx] = h;                       // becomes h_in for this chunk
    h = ap*h + he;
  }
}

// Pass C: replay chunk from h_in, in-register y-dot over n, fuse ymix -> bf16 out.
__global__ __launch_bounds__(256) void scan_final_kernel(const float* __restrict__ delta,
    const float* __restrict__ xc, const float* __restrict__ dbl,
    const float* __restrict__ xz, const float* __restrict__ Dv,
    const float* __restrict__ Alog, const float* __restrict__ hin,
    u16* __restrict__ yb){
  __shared__ float sBC[CL_][32];
  int tid = threadIdx.x;
  int d = blockIdx.x*256 + tid;
  int bych = blockIdx.y;
  int b = bych >> 4, ch = bych & (NCH_-1);
  int base = b*NP_ + ch*CL_;
  for (int i = tid; i < CL_*32; i += 256){
    int t = i >> 5, c = i & 31;
    sBC[t][c] = dbl[(size_t)(base+t)*64 + 32 + c];
  }
  float A[NS_], h[NS_];
  size_t o = ((size_t)bych*DI_ + d)*NS_;
  #pragma unroll
  for (int k = 0; k < NS_; k++){
    A[k] = -__expf(Alog[(size_t)d*NS_ + k]);
    h[k] = hin[o + k];
  }
  float Dvd = Dv[d];
  __syncthreads();
  #pragma unroll
  for (int t = 0; t < CL_; t++){
    int row = base + t;
    float de = delta[(size_t)row*DI_ + d];
    float xv = xc[(size_t)row*DI_ + d];
    float zz = xz[(size_t)row*(2*DI_) + DI_ + d];
    float cde = de*xv;
    float p = 0.f;
    #pragma unroll
    for (int k = 0; k < NS_; k++){
      float a = __expf(de*A[k]);
      h[k] = a*h[k] + cde*sBC[t][k];
      p += h[k]*sBC[t][16+k];
    }
    yb[(size_t)row*DI_ + d] = f2bf((p + xv*Dvd) * silu_f(zz));
  }
}

// ---------------- head GEMM1 partials ----------------
__global__ __launch_bounds__(256) void head1_kernel(const float* __restrict__ u,
    const float* __restrict__ hW1, float* __restrict__ partial){
  const int KTOT = DM_*NP_;        // 131072
  const int KLEN = KTOT/16;        // 8192
  int nidx = blockIdx.x;           // 0..127
  int kc   = blockIdx.y;           // 0..15
  int tid  = threadIdx.x;
  float acc[8] = {};
  const float* w = hW1 + (size_t)nidx*KTOT;
  for (int k = kc*KLEN + tid; k < (kc+1)*KLEN; k += 256){
    float wv = w[k];
    #pragma unroll
    for (int m = 0; m < 8; m++) acc[m] += u[(size_t)m*KTOT + k]*wv;
  }
  __shared__ float red[256];
  #pragma unroll
  for (int m = 0; m < 8; m++){
    red[tid] = acc[m]; __syncthreads();
    for (int s=128;s>0;s>>=1){ if (tid<s) red[tid]+=red[tid+s]; __syncthreads(); }
    if (tid == 0) partial[((size_t)kc*128 + nidx)*8 + m] = red[0];
    __syncthreads();
  }
}

__global__ void head_combine_kernel(const float* __restrict__ partial,
    const float* __restrict__ hb1, float* __restrict__ t1){
  int idx = blockIdx.x*256 + threadIdx.x;  // n*8+m, 1024 total
  if (idx >= 128*8) return;
  int n = idx >> 3, m = idx & 7;
  float s = hb1[n];
  #pragma unroll
  for (int kc = 0; kc < 16; kc++) s += partial[((size_t)kc*128 + n)*8 + m];
  float ge = 0.5f*s*(1.f + erff(s*0.70710678118f));
  t1[m*128 + n] = ge;
}

__global__ void head2_kernel(const float* __restrict__ t1, const float* __restrict__ hW2,
                             const float* __restrict__ hb2, float* __restrict__ out){
  int idx = blockIdx.x*128 + threadIdx.x;  // 8*96
  if (idx >= B_*PRED_) return;
  int m = idx / PRED_, q = idx % PRED_;
  float s = hb2[q];
  #pragma unroll 16
  for (int k = 0; k < 2*CD_; k++) s += t1[m*128 + k]*hW2[q*128 + k];
  out[idx] = s;
}

// ---------------- prep: transposes + bf16 weight conversions ----------------
__global__ void prep_kernel(const float* __restrict__ W_dt, const float* __restrict__ W_x,
                            const float* __restrict__ W_in, const float* __restrict__ W_out,
                            float* __restrict__ wdtT, float* __restrict__ wxT,
                            u16* __restrict__ WinB, u16* __restrict__ WoutB){
  int idx = blockIdx.x*256 + threadIdx.x;
  if (idx < NL_*DTR_*DI_){
    int l = idx / (DTR_*DI_); int rem = idx % (DTR_*DI_);
    int r = rem / DI_; int d = rem % DI_;
    wdtT[idx] = W_dt[((size_t)l*DI_ + d)*DTR_ + r];
  }
  if (idx < NL_*DI_*64){
    int l = idx / (DI_*64); int rem = idx % (DI_*64);
    int k = rem / 64; int e = rem % 64;
    wxT[idx] = W_x[((size_t)l*64 + e)*DI_ + k];
  }
  if (idx < NL_*2*DI_*DM_) WinB[idx]  = f2bf(W_in[idx]);
  if (idx < NL_*DM_*DI_)   WoutB[idx] = f2bf(W_out[idx]);
}

extern "C" void kernel_launch(void* const* d_in, const int* in_sizes, int n_in,
                              void* d_out, int out_size, void* d_ws, size_t ws_size,
                              hipStream_t stream) {
  const float* x      = (const float*)d_in[0];
  const float* in_g   = (const float*)d_in[1];
  const float* in_b   = (const float*)d_in[2];
  const float* pe_W   = (const float*)d_in[3];
  const float* pe_b   = (const float*)d_in[4];
  const float* ln_g   = (const float*)d_in[5];
  const float* ln_b   = (const float*)d_in[6];
  const float* W_in   = (const float*)d_in[7];
  const float* conv_W = (const float*)d_in[8];
  const float* conv_b = (const float*)d_in[9];
  const float* W_x    = (const float*)d_in[10];
  const float* W_dt   = (const float*)d_in[11];
  const float* b_dt   = (const float*)d_in[12];
  const float* A_log  = (const float*)d_in[13];
  const float* Dskip  = (const float*)d_in[14];
  const float* W_out  = (const float*)d_in[15];
  const float* fn_g   = (const float*)d_in[16];
  const float* fn_b   = (const float*)d_in[17];
  const float* hW1    = (const float*)d_in[18];
  const float* hb1    = (const float*)d_in[19];
  const float* hW2    = (const float*)d_in[20];
  const float* hb2    = (const float*)d_in[21];

  float* ws    = (float*)d_ws;
  float* h     = ws;                    // 1,048,576 f
  float* un    = h     + 1048576;       // 1,048,576 f
  float* xz    = un    + 1048576;       // 4,194,304 f
  float* xc    = xz    + 4194304;       // 2,097,152 f
  float* dblb  = xc    + 2097152;       //   131,072 f
  float* delta = dblb  + 131072;        // 2,097,152 f
  float* y     = delta + 2097152;       // 2,097,152 f   (reused: hend/hin)
  float* wdtT  = y     + 2097152;       //   131,072 f
  float* wxT   = wdtT  + 131072;        //   262,144 f
  float* bf_rgn= wxT   + 262144;
  u16*   unb   = (u16*)bf_rgn;                  // 1,048,576 u16
  u16*   yb    = (u16*)(bf_rgn + 524288);       // 2,097,152 u16
  u16*   WinB  = (u16*)(bf_rgn + 524288 + 1048576);            // 4,194,304 u16
  u16*   WoutB = (u16*)(bf_rgn + 524288 + 1048576 + 2097152);  // 2,097,152 u16
  float* aprod = ws + 17825792;         // 2,097,152 f  (total 19,922,944 f = 79.7 MB)
  float* hend  = y;                     // [B*NCH][DI][NS] = 2,097,152 f; becomes hin after pass B
  float* xln     = y;                   // prologue-only, overlays y
  float* partial = xz;                  // epilogue-only, overlays xz
  float* t1      = xz + 16384;

  prep_kernel<<<16384, 256, 0, stream>>>(W_dt, W_x, W_in, W_out, wdtT, wxT, WinB, WoutB);
  ln7_kernel<<<(B_*SEQ_+255)/256, 256, 0, stream>>>(x, in_g, in_b, xln);
  embed_kernel<<<TOK_, 256, 0, stream>>>(xln, pe_W, pe_b, h);

  for (int l = 0; l < NL_; l++){
    ln512_kernel<<<TOK_, 256, 0, stream>>>(h, ln_g + l*DM_, ln_b + l*DM_, un, unb);
    gemm_bf16<128,128,false><<<dim3(2*DI_/128, TOK_/128), 256, 0, stream>>>(
        unb, WinB + (size_t)l*2*DI_*DM_, xz, DM_, DM_, DM_, 2*DI_);
    conv_silu_kernel<<<(TOK_*DI_)/256, 256, 0, stream>>>(
        xz, conv_W + (size_t)l*DI_*DC_, conv_b + (size_t)l*DI_, xc);
    dbl_kernel<<<TOK_/4, 256, 0, stream>>>(xc, wxT + (size_t)l*DI_*64, dblb);
    delta_kernel<<<dim3(DI_/256, TOK_), 256, 0, stream>>>(
        dblb, wdtT + (size_t)l*DTR_*DI_, b_dt + (size_t)l*DI_, delta);
    scan_part_kernel<<<dim3(DI_/256, B_*NCH_), 256, 0, stream>>>(
        delta, xc, dblb, A_log + (size_t)l*DI_*NS_, hend, aprod);
    scan_fix_kernel<<<(B_*DI_*NS_)/256, 256, 0, stream>>>(aprod, hend);
    scan_final_kernel<<<dim3(DI_/256, B_*NCH_), 256, 0, stream>>>(
        delta, xc, dblb, xz, Dskip + (size_t)l*DI_, A_log + (size_t)l*DI_*NS_, hend, yb);
    gemm_bf16<64,64,true><<<dim3(DM_/64, TOK_/64), 256, 0, stream>>>(
        yb, WoutB + (size_t)l*DM_*DI_, h, DI_, DI_, DI_, DM_);
  }

  ln512_kernel<<<TOK_, 256, 0, stream>>>(h, fn_g, fn_b, un, unb);
  head1_kernel<<<dim3(128, 16), 256, 0, stream>>>(un, hW1, partial);
  head_combine_kernel<<<4, 256, 0, stream>>>(partial, hb1, t1);
  head2_kernel<<<6, 128, 0, stream>>>(t1, hW2, hb2, (float*)d_out);
}